// Round 4
// baseline (237.340 us; speedup 1.0000x reference)
//
#include <hip/hip_runtime.h>
#include <stdint.h>
#include <math.h>

#define NN 8192        // nodes
#define NE 262144      // edges
#define WPR 256        // 32-bit words per dense adjacency row
#define CAP 96         // ELL slots/row; max unique degree ~56, P(overflow)~1e-15

struct TFKey { uint32_t a, b; };

// JAX threefry2x32 (rot 13,15,26,6 / 17,29,16,24; 20 rounds)
__host__ __device__ static inline void tf2x32(uint32_t k0, uint32_t k1,
                                              uint32_t x0, uint32_t x1,
                                              uint32_t* o0, uint32_t* o1) {
  uint32_t ks2 = k0 ^ k1 ^ 0x1BD11BDAu;
#define TF_ROT(x, r) (((x) << (r)) | ((x) >> (32 - (r))))
#define TF_R(r) { x0 += x1; x1 = TF_ROT(x1, r); x1 ^= x0; }
  x0 += k0; x1 += k1;
  TF_R(13) TF_R(15) TF_R(26) TF_R(6)
  x0 += k1;  x1 += ks2 + 1u;
  TF_R(17) TF_R(29) TF_R(16) TF_R(24)
  x0 += ks2; x1 += k0 + 2u;
  TF_R(13) TF_R(15) TF_R(26) TF_R(6)
  x0 += k0;  x1 += k1 + 3u;
  TF_R(17) TF_R(29) TF_R(16) TF_R(24)
  x0 += k1;  x1 += ks2 + 4u;
  TF_R(13) TF_R(15) TF_R(26) TF_R(6)
  x0 += ks2; x1 += k0 + 5u;
  *o0 = x0; *o1 = x1;
#undef TF_R
#undef TF_ROT
}

// JAX partitionable 32-bit random_bits at flat index n: bits = o0^o1 @ (0,n);
// uniform f32 = bitcast((bits>>9)|0x3f800000) - 1.0f  (exact 2^-23 grid)
__device__ static inline float tf_uniform(TFKey k, uint32_t n) {
  uint32_t o0, o1;
  tf2x32(k.a, k.b, 0u, n, &o0, &o1);
  uint32_t bits = o0 ^ o1;
  return __uint_as_float((bits >> 9) | 0x3f800000u) - 1.0f;
}

// ---- shared device bodies (f64 accumulation order identical to verified) ----

// H = A@W, f64 acc -> f32 round; one output element per thread t.
// float4 A-row loads (16B/lane); a0 takes even k, a1 odd k — exact same
// per-chain addition order as the verified scalar version.
template<int K, int N>
__device__ __forceinline__ void gemm_elem(const float* __restrict__ A,
                                          const float* __restrict__ Wb,
                                          float* __restrict__ H, int t) {
  int i = t / N, c = t % N;
  const float4* Arow = (const float4*)(A + (size_t)i * K);
  double a0 = 0.0, a1 = 0.0;
#pragma unroll 4
  for (int k4 = 0; k4 < K / 4; ++k4) {
    float4 av = Arow[k4];
    int k = k4 * 4;
    a0 += (double)av.x * (double)Wb[(size_t)k * N + c];
    a1 += (double)av.y * (double)Wb[(size_t)(k + 1) * N + c];
    a0 += (double)av.z * (double)Wb[(size_t)(k + 2) * N + c];
    a1 += (double)av.w * (double)Wb[(size_t)(k + 3) * N + c];
  }
  H[t] = (float)(a0 + a1);
}

// z_i = dropout(relu(sum_j f32(di*dj)*h_j + f32(di*di)*h_i + b)); one row/wave.
// DEG0: layer-0 path — dinv values computed on the fly from final deg[] with
// the bit-identical expression (float)(1.0/sqrt((double)(deg+1))).
template<int D, bool DEG0>
__device__ __forceinline__ void agg_row(const uint16_t* __restrict__ cols,
                                        const uint32_t* __restrict__ deg,
                                        const uint8_t* __restrict__ mask,
                                        const float* __restrict__ h,
                                        const float* __restrict__ dinv,
                                        const float* __restrict__ bias,
                                        TFKey kd, float* __restrict__ zout,
                                        int i, int lane) {
  bool act = lane < D;
  uint32_t du = deg[i];
  float di = DEG0 ? (float)(1.0 / sqrt((double)(du + 1u))) : dinv[i];
  uint32_t d = du < (uint32_t)CAP ? du : (uint32_t)CAP;
  const uint16_t* cr = cols + (size_t)i * CAP;
  const uint8_t* mr = (!DEG0 && mask) ? mask + (size_t)i * CAP : (const uint8_t*)nullptr;
  double a0 = 0.0, a1 = 0.0;
  uint32_t s = 0;
  for (; s + 1 < d; s += 2) {                 // 2 accumulators: half the chain
    int j0 = cr[s], j1 = cr[s + 1];
    bool m0 = DEG0 || !mr || mr[s], m1 = DEG0 || !mr || mr[s + 1];
    if (act) {
      if (m0) {
        float dj0 = DEG0 ? (float)(1.0 / sqrt((double)(deg[j0] + 1u))) : dinv[j0];
        float c0 = di * dj0;
        a0 += (double)c0 * (double)h[(size_t)j0 * D + lane];
      }
      if (m1) {
        float dj1 = DEG0 ? (float)(1.0 / sqrt((double)(deg[j1] + 1u))) : dinv[j1];
        float c1 = di * dj1;
        a1 += (double)c1 * (double)h[(size_t)j1 * D + lane];
      }
    }
  }
  if (s < d && (DEG0 || !mr || mr[s]) && act) {
    int j = cr[s];
    float dj = DEG0 ? (float)(1.0 / sqrt((double)(deg[j] + 1u))) : dinv[j];
    float c = di * dj;
    a0 += (double)c * (double)h[(size_t)j * D + lane];
  }
  if (act) {
    double acc = a0 + a1;
    float cI = di * di;                       // +I diagonal term, f32
    acc += (double)cI * (double)h[(size_t)i * D + lane];
    float sv = (float)acc;                    // matmul result rounded f32
    float pre = fmaxf(sv + bias[lane], 0.0f); // bias + relu (f32)
    float u = tf_uniform(kd, (uint32_t)(i * D + lane));
    zout[(size_t)i * D + lane] = (u < 0.9f) ? (pre / 0.9f) : 0.0f;
  }
}

// resample row i: 4 edges in flight (16 lanes/edge, float4/lane); f64 dot via
// shfl tree; survivor count fuses the NEXT layer's dinv
__device__ __forceinline__ void sample_row(const uint16_t* __restrict__ cols,
                                           const uint32_t* __restrict__ deg,
                                           const float* __restrict__ z,
                                           TFKey kb, uint8_t* __restrict__ mask,
                                           float* __restrict__ dinv,
                                           int i, int lane) {
  int g = lane >> 4, l = lane & 15;           // edge-group 0..3, lane-in-group
  float4 zi = *(const float4*)(z + (size_t)i * 64 + 4 * l);
  uint32_t du = deg[i];
  uint32_t d = du < (uint32_t)CAP ? du : (uint32_t)CAP;
  const uint16_t* cr = cols + (size_t)i * CAP;
  uint8_t* mr = mask + (size_t)i * CAP;
  int cnt = 0;
  for (uint32_t base = 0; base < d; base += 4) {
    uint32_t s = base + (uint32_t)g;
    bool on = s < d;
    int j = 0;
    if (on) j = cr[s];
    float4 b = *(const float4*)(z + (size_t)j * 64 + 4 * l);
    double p = (double)zi.x * (double)b.x + (double)zi.y * (double)b.y
             + (double)zi.z * (double)b.z + (double)zi.w * (double)b.w;
    p += __shfl_xor(p, 1, 64);                // 16-lane tree: stays in group
    p += __shfl_xor(p, 2, 64);
    p += __shfl_xor(p, 4, 64);
    p += __shfl_xor(p, 8, 64);
    if (l == 0 && on) {
      float dot32 = (float)p;                 // ref's f32 z@z.T entry
      float prob = (float)(1.0 / (1.0 + exp(-(double)dot32)));
      float u = tf_uniform(kb, (uint32_t)((i << 13) | j));
      uint8_t m = (u < prob) ? 1u : 0u;
      mr[s] = m;
      cnt += m;
    }
  }
  cnt += __shfl_xor(cnt, 16, 64);             // sum the 4 group leaders
  cnt += __shfl_xor(cnt, 32, 64);
  if (lane == 0) dinv[i] = (float)(1.0 / sqrt((double)(cnt + 1)));
}

// ==============================  kernels  ==================================

// zero dense bitmask (8 MB) + deg; block 0 probes int64-vs-int32 storage
__global__ __launch_bounds__(256) void k_init(const int* __restrict__ e,
                                              uint32_t* __restrict__ dense,
                                              uint32_t* __restrict__ deg,
                                              uint32_t* __restrict__ flag) {
  uint32_t t = blockIdx.x * 256 + threadIdx.x;
  ((uint4*)dense)[t] = make_uint4(0u, 0u, 0u, 0u);   // 2048 blk * 16B = 8 MB
  if (t < NN) deg[t] = 0u;
  if (blockIdx.x == 0) {
    const unsigned long long* p = (const unsigned long long*)e;
    bool bad = false;
    for (int q = 0; q < 8; ++q)                // 2048 u64 samples: decisive
      bad |= (p[threadIdx.x * 8 + q] >= 8192ull);
    __shared__ uint32_t sh[4];
    unsigned long long b = __ballot(bad);
    if ((threadIdx.x & 63) == 0) sh[threadIdx.x >> 6] = (b != 0ull) ? 1u : 0u;
    __syncthreads();
    if (threadIdx.x == 0) flag[0] = sh[0] | sh[1] | sh[2] | sh[3];
  }
}

// blocks [0,GB0): gemm0 x@W0 -> h; rest: dedup'd ELL build (bitmask atomicOr
// returns old word -> first setter claims a slot). deg is FINAL after this.
__global__ __launch_bounds__(256) void k_gb(const float* __restrict__ x,
                                            const float* __restrict__ W0,
                                            float* __restrict__ h,
                                            const int* __restrict__ e,
                                            const uint32_t* __restrict__ flag,
                                            uint32_t* __restrict__ dense,
                                            uint32_t* __restrict__ deg,
                                            uint16_t* __restrict__ cols) {
  constexpr int GB0 = NN * 64 / 256;
  if (blockIdx.x < GB0) {
    gemm_elem<128, 64>(x, W0, h, blockIdx.x * 256 + threadIdx.x);
  } else {
    int ed = (blockIdx.x - GB0) * 256 + threadIdx.x;
    int r, c;
    if (*flag) { r = e[ed]; c = e[ed + NE]; }
    else { const long long* p = (const long long*)e; r = (int)p[ed]; c = (int)p[ed + NE]; }
    uint32_t bit = 1u << (c & 31);
    uint32_t old = atomicOr(&dense[(size_t)r * WPR + (c >> 5)], bit);
    if (!(old & bit)) {
      uint32_t s = atomicAdd(&deg[r], 1u);
      if (s < CAP) cols[(size_t)r * CAP + s] = (uint16_t)c;  // memory safety
    }
  }
}

template<int D, bool DEG0>
__global__ __launch_bounds__(256) void k_agg(const uint16_t* __restrict__ cols,
                                             const uint32_t* __restrict__ deg,
                                             const uint8_t* __restrict__ mask,
                                             const float* __restrict__ h,
                                             const float* __restrict__ dinv,
                                             const float* __restrict__ bias,
                                             TFKey kd, float* __restrict__ zout) {
  int lane = threadIdx.x & 63;
  int i = blockIdx.x * 4 + (threadIdx.x >> 6);
  agg_row<D, DEG0>(cols, deg, mask, h, dinv, bias, kd, zout, i, lane);
}

// blocks [0,GB): gemm z@W -> h (next layer); rest: resample rows (mask + next
// dinv). Independent: sample reads z/writes mask,dinv; gemm reads z/writes h.
template<int K, int N>
__global__ __launch_bounds__(256) void k_sg(const float* __restrict__ z,
                                            const float* __restrict__ Wb,
                                            float* __restrict__ h,
                                            const uint16_t* __restrict__ cols,
                                            const uint32_t* __restrict__ deg,
                                            TFKey kb,
                                            uint8_t* __restrict__ mask,
                                            float* __restrict__ dinv) {
  constexpr int GB = NN * N / 256;
  if (blockIdx.x < GB) {
    gemm_elem<K, N>(z, Wb, h, blockIdx.x * 256 + threadIdx.x);
  } else {
    int lane = threadIdx.x & 63;
    int i = (blockIdx.x - GB) * 4 + (threadIdx.x >> 6);
    sample_row(cols, deg, z, kb, mask, dinv, i, lane);
  }
}

// ==============================  launch  ===================================

extern "C" void kernel_launch(void* const* d_in, const int* in_sizes, int n_in,
                              void* d_out, int out_size, void* d_ws, size_t ws_size,
                              hipStream_t stream) {
  (void)in_sizes; (void)n_in; (void)out_size; (void)ws_size;
  const float* x  = (const float*)d_in[0];
  const float* W0 = (const float*)d_in[1];
  const float* b0 = (const float*)d_in[2];
  const float* W1 = (const float*)d_in[3];
  const float* b1 = (const float*)d_in[4];
  const float* W2 = (const float*)d_in[5];
  const float* b2 = (const float*)d_in[6];
  const int* ei = (const int*)d_in[7];
  float* out = (float*)d_out;

  // Workspace (~15 MB): dense lives only through k_gb; h no longer overlays
  // it (gemm0 runs concurrently with build), so all buffers are disjoint.
  uint8_t* base = (uint8_t*)d_ws;
  uint32_t* dense = (uint32_t*)(base);                       // [0, 8 MB)
  float* h        = (float*)(base + 8388608);                // [8, 10 MB)
  float* z        = (float*)(base + 10485760);               // [10, 12 MB)
  uint32_t* deg   = (uint32_t*)(base + 12582912);            // 32 KB
  uint16_t* cols  = (uint16_t*)(base + 12582912 + 32768);    // ELL cols, 1.5 MB
  uint8_t*  mask  = (uint8_t*)(base + 12582912 + 32768 + 1572864);          // 768 KB
  float*    dinv  = (float*)(base + 12582912 + 32768 + 1572864 + 786432);   // 32 KB
  uint32_t* flag  = (uint32_t*)(base + 12582912 + 32768 + 1572864 + 786432 + 32768);

  // JAX partitionable key chain: k_i = fold_in(key(42), i); kd@(0,0), kb@(0,1)
  TFKey kd[3], kb[3];
  for (uint32_t i = 0; i < 3; ++i) {
    uint32_t la, lb;
    tf2x32(0u, 42u, 0u, i, &la, &lb);
    tf2x32(la, lb, 0u, 0u, &kd[i].a, &kd[i].b);
    tf2x32(la, lb, 0u, 1u, &kb[i].a, &kb[i].b);
  }

  // 7-node pipeline — the dependency-depth minimum for this algorithm:
  // init -> (gemm0 || build) -> agg0 -> (sample0 || gemm1) -> agg1
  //      -> (sample1 || gemm2) -> agg2
  k_init<<<NN * WPR / (4 * 256), 256, 0, stream>>>(ei, dense, deg, flag);
  k_gb  <<<NN * 64 / 256 + NE / 256, 256, 0, stream>>>(x, W0, h, ei, flag, dense, deg, cols);
  k_agg<64, true><<<NN / 4, 256, 0, stream>>>(cols, deg, nullptr, h, dinv, b0, kd[0], z);
  k_sg<64, 64><<<NN * 64 / 256 + NN / 4, 256, 0, stream>>>(z, W1, h, cols, deg, kb[0], mask, dinv);
  k_agg<64, false><<<NN / 4, 256, 0, stream>>>(cols, deg, mask, h, dinv, b1, kd[1], z);
  k_sg<64, 32><<<NN * 32 / 256 + NN / 4, 256, 0, stream>>>(z, W2, h, cols, deg, kb[1], mask, dinv);
  k_agg<32, false><<<NN / 4, 256, 0, stream>>>(cols, deg, mask, h, dinv, b2, kd[2], out);
}

// Round 5
// 220.778 us; speedup vs baseline: 1.0750x; 1.0750x over previous
//
#include <hip/hip_runtime.h>
#include <stdint.h>
#include <math.h>

#define NN 8192        // nodes
#define NE 262144      // edges
#define CAP 96         // ELL slots/row; max RAW multiplicity ~60 (mean 32, +11sigma)

struct TFKey { uint32_t a, b; };

// JAX threefry2x32 (rot 13,15,26,6 / 17,29,16,24; 20 rounds)
__host__ __device__ static inline void tf2x32(uint32_t k0, uint32_t k1,
                                              uint32_t x0, uint32_t x1,
                                              uint32_t* o0, uint32_t* o1) {
  uint32_t ks2 = k0 ^ k1 ^ 0x1BD11BDAu;
#define TF_ROT(x, r) (((x) << (r)) | ((x) >> (32 - (r))))
#define TF_R(r) { x0 += x1; x1 = TF_ROT(x1, r); x1 ^= x0; }
  x0 += k0; x1 += k1;
  TF_R(13) TF_R(15) TF_R(26) TF_R(6)
  x0 += k1;  x1 += ks2 + 1u;
  TF_R(17) TF_R(29) TF_R(16) TF_R(24)
  x0 += ks2; x1 += k0 + 2u;
  TF_R(13) TF_R(15) TF_R(26) TF_R(6)
  x0 += k0;  x1 += k1 + 3u;
  TF_R(17) TF_R(29) TF_R(16) TF_R(24)
  x0 += k1;  x1 += ks2 + 4u;
  TF_R(13) TF_R(15) TF_R(26) TF_R(6)
  x0 += ks2; x1 += k0 + 5u;
  *o0 = x0; *o1 = x1;
#undef TF_R
#undef TF_ROT
}

// JAX partitionable 32-bit random_bits at flat index n: bits = o0^o1 @ (0,n);
// uniform f32 = bitcast((bits>>9)|0x3f800000) - 1.0f  (exact 2^-23 grid)
__device__ static inline float tf_uniform(TFKey k, uint32_t n) {
  uint32_t o0, o1;
  tf2x32(k.a, k.b, 0u, n, &o0, &o1);
  uint32_t bits = o0 ^ o1;
  return __uint_as_float((bits >> 9) | 0x3f800000u) - 1.0f;
}

// ---- shared device bodies ----

// H = A@W, f64 acc -> f32 round; one output element per thread t.
// float4 A-row loads (16B/lane); a0 takes even k, a1 odd k — exact same
// per-chain addition order as the scalar version (verified bit-identical R4).
template<int K, int N>
__device__ __forceinline__ void gemm_elem(const float* __restrict__ A,
                                          const float* __restrict__ Wb,
                                          float* __restrict__ H, int t) {
  int i = t / N, c = t % N;
  const float4* Arow = (const float4*)(A + (size_t)i * K);
  double a0 = 0.0, a1 = 0.0;
#pragma unroll 4
  for (int k4 = 0; k4 < K / 4; ++k4) {
    float4 av = Arow[k4];
    int k = k4 * 4;
    a0 += (double)av.x * (double)Wb[(size_t)k * N + c];
    a1 += (double)av.y * (double)Wb[(size_t)(k + 1) * N + c];
    a0 += (double)av.z * (double)Wb[(size_t)(k + 2) * N + c];
    a1 += (double)av.w * (double)Wb[(size_t)(k + 3) * N + c];
  }
  H[t] = (float)(a0 + a1);
}

// z_i = dropout(relu(sum_j f32(di*dj)*h_j + f32(di*di)*h_i + b)); one row/wave
template<int D>
__device__ __forceinline__ void agg_row(const uint16_t* __restrict__ cols,
                                        const uint32_t* __restrict__ deg,
                                        const uint8_t* __restrict__ mask,
                                        const float* __restrict__ h,
                                        const float* __restrict__ dinv,
                                        const float* __restrict__ bias,
                                        TFKey kd, float* __restrict__ zout,
                                        int i, int lane) {
  bool act = lane < D;
  float di = dinv[i];
  uint32_t du = deg[i];
  uint32_t d = du < (uint32_t)CAP ? du : (uint32_t)CAP;
  const uint16_t* cr = cols + (size_t)i * CAP;
  const uint8_t* mr = mask ? mask + (size_t)i * CAP : (const uint8_t*)nullptr;
  double a0 = 0.0, a1 = 0.0;
  uint32_t s = 0;
  for (; s + 1 < d; s += 2) {                 // 2 accumulators: half the chain
    int j0 = cr[s], j1 = cr[s + 1];
    bool m0 = !mr || mr[s], m1 = !mr || mr[s + 1];
    if (act) {
      if (m0) { float c0 = di * dinv[j0]; a0 += (double)c0 * (double)h[(size_t)j0 * D + lane]; }
      if (m1) { float c1 = di * dinv[j1]; a1 += (double)c1 * (double)h[(size_t)j1 * D + lane]; }
    }
  }
  if (s < d && (!mr || mr[s]) && act) {
    int j = cr[s];
    float c = di * dinv[j];
    a0 += (double)c * (double)h[(size_t)j * D + lane];
  }
  if (act) {
    double acc = a0 + a1;
    float cI = di * di;                       // +I diagonal term, f32
    acc += (double)cI * (double)h[(size_t)i * D + lane];
    float sv = (float)acc;                    // matmul result rounded f32
    float pre = fmaxf(sv + bias[lane], 0.0f); // bias + relu (f32)
    float u = tf_uniform(kd, (uint32_t)(i * D + lane));
    zout[(size_t)i * D + lane] = (u < 0.9f) ? (pre / 0.9f) : 0.0f;
  }
}

// resample row i: 4 edges in flight (16 lanes/edge, float4/lane); f64 dot via
// shfl tree; survivor count fuses the NEXT layer's dinv
__device__ __forceinline__ void sample_row(const uint16_t* __restrict__ cols,
                                           const uint32_t* __restrict__ deg,
                                           const float* __restrict__ z,
                                           TFKey kb, uint8_t* __restrict__ mask,
                                           float* __restrict__ dinv,
                                           int i, int lane) {
  int g = lane >> 4, l = lane & 15;           // edge-group 0..3, lane-in-group
  float4 zi = *(const float4*)(z + (size_t)i * 64 + 4 * l);
  uint32_t du = deg[i];
  uint32_t d = du < (uint32_t)CAP ? du : (uint32_t)CAP;
  const uint16_t* cr = cols + (size_t)i * CAP;
  uint8_t* mr = mask + (size_t)i * CAP;
  int cnt = 0;
  for (uint32_t base = 0; base < d; base += 4) {
    uint32_t s = base + (uint32_t)g;
    bool on = s < d;
    int j = 0;
    if (on) j = cr[s];
    float4 b = *(const float4*)(z + (size_t)j * 64 + 4 * l);
    double p = (double)zi.x * (double)b.x + (double)zi.y * (double)b.y
             + (double)zi.z * (double)b.z + (double)zi.w * (double)b.w;
    p += __shfl_xor(p, 1, 64);                // 16-lane tree: stays in group
    p += __shfl_xor(p, 2, 64);
    p += __shfl_xor(p, 4, 64);
    p += __shfl_xor(p, 8, 64);
    if (l == 0 && on) {
      float dot32 = (float)p;                 // ref's f32 z@z.T entry
      float prob = (float)(1.0 / (1.0 + exp(-(double)dot32)));
      float u = tf_uniform(kb, (uint32_t)((i << 13) | j));
      uint8_t m = (u < prob) ? 1u : 0u;
      mr[s] = m;
      cnt += m;
    }
  }
  cnt += __shfl_xor(cnt, 16, 64);             // sum the 4 group leaders
  cnt += __shfl_xor(cnt, 32, 64);
  if (lane == 0) dinv[i] = (float)(1.0 / sqrt((double)(cnt + 1)));
}

// ==============================  kernels  ==================================

// zero deg; block 0 probes edge_index storage (int64 with vals<8192 vs int32)
__global__ __launch_bounds__(256) void k_init0(const int* __restrict__ e,
                                               uint32_t* __restrict__ deg,
                                               uint32_t* __restrict__ flag) {
  uint32_t t = blockIdx.x * 256 + threadIdx.x;
  deg[t] = 0u;                                 // grid = NN/256 blocks
  if (blockIdx.x == 0) {
    const unsigned long long* p = (const unsigned long long*)e;
    bool bad = false;
    for (int q = 0; q < 8; ++q)                // 2048 u64 samples: decisive
      bad |= (p[threadIdx.x * 8 + q] >= 8192ull);
    __shared__ uint32_t sh[4];
    unsigned long long b = __ballot(bad);
    if ((threadIdx.x & 63) == 0) sh[threadIdx.x >> 6] = (b != 0ull) ? 1u : 0u;
    __syncthreads();
    if (threadIdx.x == 0) flag[0] = sh[0] | sh[1] | sh[2] | sh[3];
  }
}

// blocks [0,GB0): gemm0 x@W0 -> h; blocks [GB0,GB0+NE/256): raw ELL scatter
// (dups included; per-row dedup happens in k_dedup). Independent workloads.
__global__ __launch_bounds__(256) void k_g0s(const float* __restrict__ x,
                                             const float* __restrict__ W0,
                                             float* __restrict__ h,
                                             const int* __restrict__ e,
                                             const uint32_t* __restrict__ flag,
                                             uint32_t* __restrict__ deg,
                                             uint16_t* __restrict__ cols) {
  constexpr int GB0 = NN * 64 / 256;
  if (blockIdx.x < GB0) {
    gemm_elem<128, 64>(x, W0, h, blockIdx.x * 256 + threadIdx.x);
  } else {
    int ed = (blockIdx.x - GB0) * 256 + threadIdx.x;
    int r, c;
    if (*flag) { r = e[ed]; c = e[ed + NE]; }
    else { const long long* p = (const long long*)e; r = (int)p[ed]; c = (int)p[ed + NE]; }
    uint32_t s = atomicAdd(&deg[r], 1u);
    if (s < CAP) cols[(size_t)r * CAP + s] = (uint16_t)c;   // memory safety
  }
}

// per-row dedup via 1KB LDS bitset per wave; in-place compaction (raw slots
// staged in registers first, so all reads precede all writes within the wave);
// writes unique deg + dinv0 = rsqrt(deg+1)
__global__ __launch_bounds__(256) void k_dedup(uint16_t* __restrict__ cols,
                                               uint32_t* __restrict__ deg,
                                               float* __restrict__ dinv) {
  __shared__ uint32_t bits[4][256];
  __shared__ uint32_t ucnt[4];
  int lane = threadIdx.x & 63;
  int wv = threadIdx.x >> 6;
  int i = blockIdx.x * 4 + wv;
  ((uint4*)bits[wv])[lane] = make_uint4(0u, 0u, 0u, 0u);
  if (lane == 0) ucnt[wv] = 0u;
  __syncthreads();
  uint32_t draw = deg[i];
  if (draw > (uint32_t)CAP) draw = (uint32_t)CAP;
  uint16_t* cr = cols + (size_t)i * CAP;
  // stage raw slots (<=96 => 2 per lane) in registers BEFORE any write
  uint32_t c0 = 0xFFFFFFFFu, c1 = 0xFFFFFFFFu;
  if ((uint32_t)lane < draw) c0 = cr[lane];
  if ((uint32_t)(lane + 64) < draw) c1 = cr[lane + 64];
  if (c0 != 0xFFFFFFFFu) {
    uint32_t bit = 1u << (c0 & 31);
    uint32_t old = atomicOr(&bits[wv][c0 >> 5], bit);
    if (!(old & bit)) { uint32_t p = atomicAdd(&ucnt[wv], 1u); cr[p] = (uint16_t)c0; }
  }
  if (c1 != 0xFFFFFFFFu) {
    uint32_t bit = 1u << (c1 & 31);
    uint32_t old = atomicOr(&bits[wv][c1 >> 5], bit);
    if (!(old & bit)) { uint32_t p = atomicAdd(&ucnt[wv], 1u); cr[p] = (uint16_t)c1; }
  }
  if (lane == 0) {
    uint32_t u = ucnt[wv];
    deg[i] = u;
    dinv[i] = (float)(1.0 / sqrt((double)(u + 1u)));
  }
}

template<int D>
__global__ __launch_bounds__(256) void k_agg(const uint16_t* __restrict__ cols,
                                             const uint32_t* __restrict__ deg,
                                             const uint8_t* __restrict__ mask,
                                             const float* __restrict__ h,
                                             const float* __restrict__ dinv,
                                             const float* __restrict__ bias,
                                             TFKey kd, float* __restrict__ zout) {
  int lane = threadIdx.x & 63;
  int i = blockIdx.x * 4 + (threadIdx.x >> 6);
  agg_row<D>(cols, deg, mask, h, dinv, bias, kd, zout, i, lane);
}

// blocks [0,GB): gemm z@W -> h (next layer); rest: resample rows (mask + next
// dinv). Independent: sample reads z/writes mask,dinv; gemm reads z/writes h.
template<int K, int N>
__global__ __launch_bounds__(256) void k_sg(const float* __restrict__ z,
                                            const float* __restrict__ Wb,
                                            float* __restrict__ h,
                                            const uint16_t* __restrict__ cols,
                                            const uint32_t* __restrict__ deg,
                                            TFKey kb,
                                            uint8_t* __restrict__ mask,
                                            float* __restrict__ dinv) {
  constexpr int GB = NN * N / 256;
  if (blockIdx.x < GB) {
    gemm_elem<K, N>(z, Wb, h, blockIdx.x * 256 + threadIdx.x);
  } else {
    int lane = threadIdx.x & 63;
    int i = (blockIdx.x - GB) * 4 + (threadIdx.x >> 6);
    sample_row(cols, deg, z, kb, mask, dinv, i, lane);
  }
}

// ==============================  launch  ===================================

extern "C" void kernel_launch(void* const* d_in, const int* in_sizes, int n_in,
                              void* d_out, int out_size, void* d_ws, size_t ws_size,
                              hipStream_t stream) {
  (void)in_sizes; (void)n_in; (void)out_size; (void)ws_size;
  const float* x  = (const float*)d_in[0];
  const float* W0 = (const float*)d_in[1];
  const float* b0 = (const float*)d_in[2];
  const float* W1 = (const float*)d_in[3];
  const float* b1 = (const float*)d_in[4];
  const float* W2 = (const float*)d_in[5];
  const float* b2 = (const float*)d_in[6];
  const int* ei = (const int*)d_in[7];
  float* out = (float*)d_out;

  // Workspace (~6.4 MB, no dense bitmask)
  uint8_t* base = (uint8_t*)d_ws;
  float* h        = (float*)(base);                          // [0, 2 MB)
  float* z        = (float*)(base + 2097152);                // [2, 4 MB)
  uint32_t* deg   = (uint32_t*)(base + 4194304);             // 32 KB
  uint16_t* cols  = (uint16_t*)(base + 4194304 + 32768);     // ELL cols, 1.5 MB
  uint8_t*  mask  = (uint8_t*)(base + 4194304 + 32768 + 1572864);           // 768 KB
  float*    dinv  = (float*)(base + 4194304 + 32768 + 1572864 + 786432);    // 32 KB
  uint32_t* flag  = (uint32_t*)(base + 4194304 + 32768 + 1572864 + 786432 + 32768);

  // JAX partitionable key chain: k_i = fold_in(key(42), i); kd@(0,0), kb@(0,1)
  TFKey kd[3], kb[3];
  for (uint32_t i = 0; i < 3; ++i) {
    uint32_t la, lb;
    tf2x32(0u, 42u, 0u, i, &la, &lb);
    tf2x32(la, lb, 0u, 0u, &kd[i].a, &kd[i].b);
    tf2x32(la, lb, 0u, 1u, &kb[i].a, &kb[i].b);
  }

  // 8-node pipeline (best-measured structure, round 3); independent
  // workloads share dispatches
  k_init0<<<NN / 256, 256, 0, stream>>>(ei, deg, flag);
  k_g0s  <<<NN * 64 / 256 + NE / 256, 256, 0, stream>>>(x, W0, h, ei, flag, deg, cols);
  k_dedup<<<NN / 4, 256, 0, stream>>>(cols, deg, dinv);
  k_agg<64><<<NN / 4, 256, 0, stream>>>(cols, deg, nullptr, h, dinv, b0, kd[0], z);
  k_sg<64, 64><<<NN * 64 / 256 + NN / 4, 256, 0, stream>>>(z, W1, h, cols, deg, kb[0], mask, dinv);
  k_agg<64><<<NN / 4, 256, 0, stream>>>(cols, deg, mask, h, dinv, b1, kd[1], z);
  k_sg<64, 32><<<NN * 32 / 256 + NN / 4, 256, 0, stream>>>(z, W2, h, cols, deg, kb[1], mask, dinv);
  k_agg<32><<<NN / 4, 256, 0, stream>>>(cols, deg, mask, h, dinv, b2, kd[2], out);
}